// Round 10
// baseline (202.286 us; speedup 1.0000x reference)
//
#include <hip/hip_runtime.h>

#define HW     3136      // 56*56
#define WIDTH  56
#define C      256
#define CR     64
#define NT     64
#define TT     8
#define PW     64        // padded row width (bf16 y)
#define PH     58        // padded rows
#define YPLANE (PH*PW)   // 3712 shorts per (nt,ch) plane
#define YBYTES ((size_t)NT * CR * YPLANE * 2)        // 30,408,704
#define CVBYTES ((size_t)NT * 9 * HW * 4)            // 7,225,344

#define BN_INV 0.9999950000374997f   // 1/sqrt(1+1e-5)

typedef __attribute__((ext_vector_type(8))) short short8;
typedef __attribute__((ext_vector_type(8))) unsigned short ushort8;
typedef __attribute__((ext_vector_type(4))) float f32x4;
typedef __attribute__((ext_vector_type(2))) float f32x2;

static __device__ __forceinline__ float relu(float v) { return fmaxf(v, 0.0f); }
static __device__ __forceinline__ float bf2f(unsigned short u) {
    return __builtin_bit_cast(float, (unsigned)u << 16);
}
static __device__ __forceinline__ float bfLO(unsigned u) {
    return __builtin_bit_cast(float, u << 16);
}
static __device__ __forceinline__ float bfHI(unsigned u) {
    return __builtin_bit_cast(float, u & 0xFFFF0000u);
}
static __device__ __forceinline__ unsigned short f2bf(float f) {
    unsigned u = __builtin_bit_cast(unsigned, f);
    unsigned r = (u + 0x7FFFu + ((u >> 16) & 1u)) >> 16;   // RNE
    return (unsigned short)r;
}
static __device__ __forceinline__ unsigned pack2(float a, float b) {
    return (unsigned)f2bf(a) | ((unsigned)f2bf(b) << 16);
}

// k0: conv21_w fp32 [64][256] -> bf16 (k-contiguous rows for A-fragments)
__global__ __launch_bounds__(256) void k0_cvt_w(const float* __restrict__ w,
                                                unsigned short* __restrict__ wbf) {
    int i = blockIdx.x * 256 + threadIdx.x;   // 0..16383
    wbf[i] = f2bf(w[i]);
}

// zero the halo cells of all 64 planes of frame nt (rows 0,57; col 0; cols 57..63)
static __device__ __forceinline__ void halo_zero(int nt, int tid,
                                                 unsigned short* __restrict__ y) {
    const int ch = tid >> 2, part = tid & 3;
    unsigned short* pl = y + ((size_t)nt * CR + ch) * YPLANE;
    if (part == 0) {
        ushort8 z = (ushort8)0;
#pragma unroll
        for (int j = 0; j < 8; ++j) *(ushort8*)(pl + j * 8) = z;          // row 0
    } else if (part == 1) {
        ushort8 z = (ushort8)0;
        unsigned short* q = pl + 57 * PW;                                  // row 57
#pragma unroll
        for (int j = 0; j < 8; ++j) *(ushort8*)(q + j * 8) = z;
    } else if (part == 2) {
        for (int r = 1; r <= 28; ++r) {
            unsigned short* q = pl + r * PW + 57;
#pragma unroll
            for (int j = 0; j < 8; ++j) q[j] = 0;
        }
    } else {
        for (int r = 29; r <= 56; ++r) {
            unsigned short* q = pl + r * PW + 57;
#pragma unroll
            for (int j = 0; j < 8; ++j) q[j] = 0;
        }
        pl[PW] = 0;                                                        // row 1 col 0
    }
}

// k1: y = relu(bn21(conv21(x))) via MFMA, bf16 padded output.
// TP=128: 24 tiles/frame (1536 blocks) + 64 halo; TP=64: 64 tail blocks.
// Collaborative staging into dbuf LDS (oct-XOR swizzle); A-frags from global
// (L2-hot), single-buffered. One barrier per K-step. LDS 17.4KB, VGPR ~120.
template<int TP>
__global__ __launch_bounds__(256) void k1_mfma(const float* __restrict__ x,
                                               const unsigned short* __restrict__ wbf,
                                               const float* __restrict__ g,
                                               const float* __restrict__ bb,
                                               unsigned short* __restrict__ y) {
    constexpr int NB = TP / 64;          // MFMA n-tiles per wave (2 or 1)
    constexpr int NQ = TP / 4;           // px-quads per tile (32 or 16)
    __shared__ unsigned short Bl[2][NQ][136];   // [buf][px-quad][4 sub x 32 + 8 pad]

    const int tid  = threadIdx.x;
    const int lane = tid & 63;
    const int wv   = tid >> 6;

    int nt, px0;
    if (TP == 128) {
        if (blockIdx.x >= 1536) { halo_zero(blockIdx.x - 1536, tid, y); return; }
        nt = blockIdx.x / 24; px0 = (blockIdx.x % 24) * 128;
    } else {
        nt = blockIdx.x; px0 = 3072;
    }

    const int p4 = tid & (NQ - 1);       // px-quad
    const int c8 = tid / NQ;             // ch-oct
    const bool active = (c8 < 4);

    const float* xbase = x + (size_t)nt * (C * HW) + px0 + 4 * p4;
    const int frow = lane & 15;
    const int hi   = lane >> 4;
    const unsigned short* abase = wbf + frow * C + hi * 8;

    f32x4 acc[NB][4];
#pragma unroll
    for (int nb = 0; nb < NB; ++nb)
#pragma unroll
        for (int mb = 0; mb < 4; ++mb) acc[nb][mb] = (f32x4)0.0f;

    f32x4  xq[8];
    short8 afr[4];

#define LOADB(KS)                                                          \
    if (active) {                                                          \
        const float* _p = xbase + (size_t)((KS) * 32 + c8 * 8) * HW;       \
        _Pragma("unroll")                                                  \
        for (int j = 0; j < 8; ++j) xq[j] = *(const f32x4*)(_p + (size_t)j * HW); \
    }

#define WRITEB(BUF)                                                        \
    if (active) {                                                          \
        _Pragma("unroll")                                                  \
        for (int i = 0; i < 4; ++i) {                                      \
            union { unsigned d[4]; short8 v; } pk;                         \
            pk.d[0] = pack2(xq[0][i], xq[1][i]);                           \
            pk.d[1] = pack2(xq[2][i], xq[3][i]);                           \
            pk.d[2] = pack2(xq[4][i], xq[5][i]);                           \
            pk.d[3] = pack2(xq[6][i], xq[7][i]);                           \
            *(short8*)&Bl[BUF][p4][i * 32 + ((c8 ^ i) & 3) * 8] = pk.v;    \
        }                                                                  \
    }

    LOADB(0)
    WRITEB(0)
    __syncthreads();

#pragma unroll
    for (int ks = 0; ks < 8; ++ks) {
        const int cb = ks & 1;
        if (ks < 7) { LOADB(ks + 1) }      // issue next global loads early
        // A-fragments (L2-hot wbf)
#pragma unroll
        for (int mb = 0; mb < 4; ++mb)
            afr[mb] = *(const short8*)(abase + mb * 16 * C + ks * 32);
        short8 bfrag[NB];
#pragma unroll
        for (int nb = 0; nb < NB; ++nb) {
            const int pxl = wv * (TP / 4) + nb * 16 + frow;
            bfrag[nb] = *(const short8*)
                &Bl[cb][pxl >> 2][(pxl & 3) * 32 + ((hi ^ (pxl & 3)) & 3) * 8];
        }
#pragma unroll
        for (int nb = 0; nb < NB; ++nb)
#pragma unroll
            for (int mb = 0; mb < 4; ++mb)
                acc[nb][mb] = __builtin_amdgcn_mfma_f32_16x16x32_bf16(
                    afr[mb], bfrag[nb], acc[nb][mb], 0, 0, 0);
        if (ks < 7) {
            WRITEB(cb ^ 1)
            __syncthreads();
        }
    }
#undef LOADB
#undef WRITEB

    // epilogue: D col = lane&15 (pixel), row = hi*4 + rr (output o); bf16 store
    unsigned short* ybase = y + (size_t)nt * CR * YPLANE;
#pragma unroll
    for (int nb = 0; nb < NB; ++nb) {
        const int p = px0 + wv * (TP / 4) + nb * 16 + frow;
        const int r = p / WIDTH;
        const int c = p - r * WIDTH;
        const int pidx = (r + 1) * PW + (c + 1);
#pragma unroll
        for (int mb = 0; mb < 4; ++mb)
#pragma unroll
            for (int rr = 0; rr < 4; ++rr) {
                int o = mb * 16 + hi * 4 + rr;
                float v = relu(fmaf(acc[nb][mb][rr], g[o] * BN_INV, bb[o]));
                ybase[(size_t)o * YPLANE + pidx] = f2bf(v);
            }
    }
}

// k2: cv[nt,k,p] = relu(bn22( (1/CR)*sum_ch y1*y2(shifted) )).
// 1568 blocks (6.1/CU). thread = (task, h); task = (nt,row,4-col grp); h = ch-octet.
__global__ __launch_bounds__(256) void k2_corr(const unsigned short* __restrict__ y,
                                               const float* __restrict__ g,
                                               const float* __restrict__ bb,
                                               float* __restrict__ cv) {
    const int gt   = blockIdx.x * 256 + threadIdx.x;   // 0..401407
    const int h    = gt & 7;                           // ch octet
    const int task = gt >> 3;                          // 0..50175
    const int nt   = task / 784;                       // 784 = 56 rows * 14 col4
    const int rm   = task - nt * 784;
    const int r    = rm / 14;
    const int cg   = rm - r * 14;
    const int c0   = cg * 4;
    const int nt2  = ((nt & (TT - 1)) < TT - 1) ? nt + 1 : nt;

    const unsigned* y1 = (const unsigned*)(y + ((size_t)nt * CR + h * 8) * YPLANE
                                             + (size_t)(r + 1) * PW + c0);
    const unsigned* y2 = (const unsigned*)(y + ((size_t)nt2 * CR + h * 8) * YPLANE
                                             + (size_t)r * PW + c0);

    float acc[9][4];
#pragma unroll
    for (int k = 0; k < 9; ++k)
#pragma unroll
        for (int px = 0; px < 4; ++px) acc[k][px] = 0.0f;

#pragma unroll
    for (int ch = 0; ch < 8; ++ch) {
        const unsigned* p1 = y1 + ch * (YPLANE / 2);
        unsigned u0 = p1[0], u1 = p1[1], u2 = p1[2];
        float a[4] = { bfHI(u0), bfLO(u1), bfHI(u1), bfLO(u2) };

        const unsigned* p2 = y2 + ch * (YPLANE / 2);
#pragma unroll
        for (int dy = 0; dy < 3; ++dy) {
            const unsigned* pr = p2 + dy * (PW / 2);
            unsigned v0 = pr[0], v1 = pr[1], v2 = pr[2];
            float w[6] = { bfLO(v0), bfHI(v0), bfLO(v1), bfHI(v1), bfLO(v2), bfHI(v2) };
#pragma unroll
            for (int dx = 0; dx < 3; ++dx) {
                int k = dy * 3 + dx;
#pragma unroll
                for (int px = 0; px < 4; ++px)
                    acc[k][px] = fmaf(a[px], w[px + dx], acc[k][px]);
            }
        }
    }

    // reduce over the 8 ch-octet lanes
#pragma unroll
    for (int k = 0; k < 9; ++k)
#pragma unroll
        for (int px = 0; px < 4; ++px) {
            float v = acc[k][px];
            v += __shfl_xor(v, 1);
            v += __shfl_xor(v, 2);
            v += __shfl_xor(v, 4);
            acc[k][px] = v;
        }

    if (h == 0) {
        float* cp = cv + (size_t)nt * 9 * HW + r * WIDTH + c0;
        const float rcr = 1.0f / CR;
#pragma unroll
        for (int k = 0; k < 9; ++k) {
            float sc = g[k] * BN_INV, bv = bb[k];
            f32x4 o;
            o.x = relu(fmaf(acc[k][0] * rcr, sc, bv));
            o.y = relu(fmaf(acc[k][1] * rcr, sc, bv));
            o.z = relu(fmaf(acc[k][2] * rcr, sc, bv));
            o.w = relu(fmaf(acc[k][3] * rcr, sc, bv));
            *(f32x4*)(cp + (size_t)k * HW) = o;
        }
    }
}

// k3: out = relu(bn23(conv22(cv)) + x). 1568 blocks; block-uniform o-half.
__global__ __launch_bounds__(256) void k3_conv22(const float* __restrict__ cv,
                                                 const float* __restrict__ w2,
                                                 const float* __restrict__ g,
                                                 const float* __restrict__ bb,
                                                 const float* __restrict__ x,
                                                 float* __restrict__ out) {
    const int ht  = (blockIdx.x >= 784);               // o-half
    const int pxg = (blockIdx.x - ht * 784) * 256 + threadIdx.x;   // 0..200703
    const int nt  = pxg / HW;
    const int p   = pxg - nt * HW;
    const int ob  = ht * 128;

    const float* cp = cv + (size_t)nt * 9 * HW + p;
    float cvv[9];
#pragma unroll
    for (int k = 0; k < 9; ++k) cvv[k] = cp[(size_t)k * HW];

    const float* xp = x   + (size_t)nt * (C * HW) + (size_t)ob * HW + p;
    float*       op = out + (size_t)nt * (C * HW) + (size_t)ob * HW + p;

#pragma unroll 8
    for (int oi = 0; oi < 128; ++oi) {
        const int o = ob + oi;
        const float* wr = w2 + o * 9;
        float xr = xp[(size_t)oi * HW];
        float s = 0.0f;
#pragma unroll
        for (int k = 0; k < 9; ++k) s = fmaf(wr[k], cvv[k], s);
        float v = fmaf(s, g[o] * BN_INV, bb[o]) + xr;
        op[(size_t)oi * HW] = relu(v);
    }
}

extern "C" void kernel_launch(void* const* d_in, const int* in_sizes, int n_in,
                              void* d_out, int out_size, void* d_ws, size_t ws_size,
                              hipStream_t stream) {
    const float* x   = (const float*)d_in[0];
    const float* w21 = (const float*)d_in[1];
    const float* g21 = (const float*)d_in[2];
    const float* b21 = (const float*)d_in[3];
    const float* g22 = (const float*)d_in[4];
    const float* b22 = (const float*)d_in[5];
    const float* w22 = (const float*)d_in[6];
    const float* g23 = (const float*)d_in[7];
    const float* b23 = (const float*)d_in[8];
    float* out = (float*)d_out;

    // ws: y bf16 padded (30.4MB) | cv fp32 (7.2MB) | wbf (32KB)
    unsigned short* yb  = (unsigned short*)d_ws;
    float*          cvb = (float*)((char*)d_ws + YBYTES);
    unsigned short* wbf = (unsigned short*)((char*)d_ws + YBYTES + CVBYTES);

    k0_cvt_w     <<<64,   256, 0, stream>>>(w21, wbf);
    k1_mfma<128> <<<1600, 256, 0, stream>>>(x, wbf, g21, b21, yb);  // 1536 tiles + 64 halo
    k1_mfma<64>  <<<64,   256, 0, stream>>>(x, wbf, g21, b21, yb);  // px 3072..3135
    k2_corr      <<<1568, 256, 0, stream>>>(yb, g22, b22, cvb);
    k3_conv22    <<<1568, 256, 0, stream>>>(cvb, w22, g23, b23, x, out);
}

// Round 11
// 201.400 us; speedup vs baseline: 1.0044x; 1.0044x over previous
//
#include <hip/hip_runtime.h>

#define HW     3136      // 56*56
#define WIDTH  56
#define C      256
#define CR     64
#define NT     64
#define TT     8
#define PW     64        // padded row width (bf16 y)
#define PH     58        // padded rows
#define YPLANE (PH*PW)   // 3712 shorts per (nt,ch) plane
#define YBYTES ((size_t)NT * CR * YPLANE * 2)        // 30,408,704
#define CVBYTES ((size_t)NT * 9 * HW * 4)            // 7,225,344

#define BN_INV 0.9999950000374997f   // 1/sqrt(1+1e-5)

typedef __attribute__((ext_vector_type(8))) short short8;
typedef __attribute__((ext_vector_type(8))) unsigned short ushort8;
typedef __attribute__((ext_vector_type(4))) float f32x4;
typedef __attribute__((ext_vector_type(2))) float f32x2;

static __device__ __forceinline__ float relu(float v) { return fmaxf(v, 0.0f); }
static __device__ __forceinline__ float bf2f(unsigned short u) {
    return __builtin_bit_cast(float, (unsigned)u << 16);
}
static __device__ __forceinline__ unsigned short f2bf(float f) {
    unsigned u = __builtin_bit_cast(unsigned, f);
    unsigned r = (u + 0x7FFFu + ((u >> 16) & 1u)) >> 16;   // RNE
    return (unsigned short)r;
}
static __device__ __forceinline__ unsigned pack2(float a, float b) {
    return (unsigned)f2bf(a) | ((unsigned)f2bf(b) << 16);
}

// k0: conv21_w fp32 [64][256] -> bf16 (k-contiguous rows for A-fragments)
__global__ __launch_bounds__(256) void k0_cvt_w(const float* __restrict__ w,
                                                unsigned short* __restrict__ wbf) {
    int i = blockIdx.x * 256 + threadIdx.x;   // 0..16383
    wbf[i] = f2bf(w[i]);
}

// zero the halo cells of all 64 planes of frame nt (rows 0,57; col 0; cols 57..63)
static __device__ __forceinline__ void halo_zero(int nt, int tid,
                                                 unsigned short* __restrict__ y) {
    const int ch = tid >> 2, part = tid & 3;
    unsigned short* pl = y + ((size_t)nt * CR + ch) * YPLANE;
    if (part == 0) {
        ushort8 z = (ushort8)0;
#pragma unroll
        for (int j = 0; j < 8; ++j) *(ushort8*)(pl + j * 8) = z;          // row 0
    } else if (part == 1) {
        ushort8 z = (ushort8)0;
        unsigned short* q = pl + 57 * PW;                                  // row 57
#pragma unroll
        for (int j = 0; j < 8; ++j) *(ushort8*)(q + j * 8) = z;
    } else if (part == 2) {
        for (int r = 1; r <= 28; ++r) {
            unsigned short* q = pl + r * PW + 57;
#pragma unroll
            for (int j = 0; j < 8; ++j) q[j] = 0;
        }
    } else {
        for (int r = 29; r <= 56; ++r) {
            unsigned short* q = pl + r * PW + 57;
#pragma unroll
            for (int j = 0; j < 8; ++j) q[j] = 0;
        }
        pl[PW] = 0;                                                        // row 1 col 0
    }
}

// k1: y = relu(bn21(conv21(x))) via MFMA, bf16 padded output.
// Block = 64 px of one frame (grid 3136 + 64 halo). Wave wv stages channels
// wv*8..wv*8+7 (lane = px, 256B/instr), wave computes px sub-tile wv*16..+15
// for all 64 o. Depth-2 global prefetch; raw s_barrier with lgkmcnt-only wait
// so prefetch loads stay in flight across the barrier (counted vmcnt).
__global__ __launch_bounds__(256) void k1_mfma(const float* __restrict__ x,
                                               const unsigned short* __restrict__ wbf,
                                               const float* __restrict__ g,
                                               const float* __restrict__ bb,
                                               unsigned short* __restrict__ y) {
    const int blk = blockIdx.x;
    const int tid = threadIdx.x;
    if (blk >= 3136) { halo_zero(blk - 3136, tid, y); return; }

    __shared__ unsigned short Bl[2][64][40];   // dbuf B-tile: 64 px x 32 ch (+pad) = 10 KB

    const int lane = tid & 63;
    const int wv   = tid >> 6;
    const int nt   = blk / 49;
    const int p0   = (blk - nt * 49) * 64;
    const int frow = lane & 15;
    const int hi   = lane >> 4;

    const float* xp = x + (size_t)nt * (C * HW) + p0 + lane;
    const unsigned short* ab = wbf + frow * C + hi * 8;

    f32x4 acc[4];
#pragma unroll
    for (int mb = 0; mb < 4; ++mb) acc[mb] = (f32x4)0.0f;

    float  xq[2][8];     // slot s&1 holds K-step s staging data
    short8 afr[2][4];    // slot s&1 holds K-step s A-fragments

#define ISSUE_X(KS, SLOT)                                                   \
    _Pragma("unroll")                                                       \
    for (int j = 0; j < 8; ++j)                                             \
        xq[SLOT][j] = xp[(size_t)((KS) * 32 + wv * 8 + j) * HW];

#define ISSUE_A(KS, SLOT)                                                   \
    _Pragma("unroll")                                                       \
    for (int mb = 0; mb < 4; ++mb)                                          \
        afr[SLOT][mb] = *(const short8*)(ab + mb * 16 * C + (KS) * 32);

#define PACK_WRITE(SLOT, BUF)                                               \
    {                                                                       \
        union { unsigned d[4]; short8 v; } pk;                              \
        pk.d[0] = pack2(xq[SLOT][0], xq[SLOT][1]);                          \
        pk.d[1] = pack2(xq[SLOT][2], xq[SLOT][3]);                          \
        pk.d[2] = pack2(xq[SLOT][4], xq[SLOT][5]);                          \
        pk.d[3] = pack2(xq[SLOT][6], xq[SLOT][7]);                          \
        *(short8*)&Bl[BUF][lane][wv * 8] = pk.v;                            \
    }

#define LDS_BARRIER                                                         \
    __builtin_amdgcn_sched_barrier(0);                                      \
    asm volatile("s_waitcnt lgkmcnt(0)" ::: "memory");                      \
    __builtin_amdgcn_s_barrier();                                           \
    __builtin_amdgcn_sched_barrier(0);

    // prolog: stage ks=0, issue ks=1 loads, A-frags for ks=0
    ISSUE_X(0, 0)
    ISSUE_A(0, 0)
    PACK_WRITE(0, 0)
    ISSUE_X(1, 1)
    LDS_BARRIER

#pragma unroll
    for (int ks = 0; ks < 8; ++ks) {
        const int cb = ks & 1;
        if (ks < 6) { ISSUE_X(ks + 2, cb) }          // depth-2 prefetch
        if (ks < 7) { ISSUE_A(ks + 1, cb ^ 1) }      // A for next step (L2-hot)
        short8 bf = *(const short8*)&Bl[cb][wv * 16 + frow][hi * 8];
#pragma unroll
        for (int mb = 0; mb < 4; ++mb)
            acc[mb] = __builtin_amdgcn_mfma_f32_16x16x32_bf16(
                afr[cb][mb], bf, acc[mb], 0, 0, 0);
        if (ks < 7) {
            PACK_WRITE(cb ^ 1, cb ^ 1)               // counted vmcnt wait (ks+1 loads)
            LDS_BARRIER
        }
    }
#undef ISSUE_X
#undef ISSUE_A
#undef PACK_WRITE
#undef LDS_BARRIER

    // epilogue: D col = lane&15 (pixel), row = hi*4 + rr (output o); bf16 store
    unsigned short* ybase = y + (size_t)nt * CR * YPLANE;
    const int p = p0 + wv * 16 + frow;
    const int r = p / WIDTH;
    const int c = p - r * WIDTH;
    const int pidx = (r + 1) * PW + (c + 1);
#pragma unroll
    for (int mb = 0; mb < 4; ++mb)
#pragma unroll
        for (int rr = 0; rr < 4; ++rr) {
            int o = mb * 16 + hi * 4 + rr;
            float v = relu(fmaf(acc[mb][rr], g[o] * BN_INV, bb[o]));
            ybase[(size_t)o * YPLANE + pidx] = f2bf(v);
        }
}

// k2: cv[nt,k,p] = relu(bn22( (1/CR) * sum_ch y1*y2(shifted) )).  (round-5 proven)
// Thread = (task, ch-quarter); task = (nt, row, 8-col group). No masks (halo).
__global__ __launch_bounds__(256) void k2_corr(const unsigned short* __restrict__ y,
                                               const float* __restrict__ g,
                                               const float* __restrict__ bb,
                                               float* __restrict__ cv) {
    int gt   = blockIdx.x * 256 + threadIdx.x;   // 0..100351
    int h    = gt & 3;                           // ch quarter
    int task = gt >> 2;                          // 0..25087
    int nt   = task / 392;                       // 392 = 56 rows * 7 cgroups
    int rm   = task - nt * 392;
    int r    = rm / 7;
    int cg   = rm - r * 7;
    int c0   = cg * 8;
    int nt2  = ((nt & (TT - 1)) < TT - 1) ? nt + 1 : nt;

    const unsigned short* y1 = y + ((size_t)nt * CR + h * 16) * YPLANE
                                 + (size_t)(r + 1) * PW + c0;
    const unsigned short* y2 = y + ((size_t)nt2 * CR + h * 16) * YPLANE
                                 + (size_t)r * PW + c0;

    float acc[9][8];
#pragma unroll
    for (int k = 0; k < 9; ++k)
#pragma unroll
        for (int px = 0; px < 8; ++px) acc[k][px] = 0.0f;

#pragma unroll 2
    for (int ch = 0; ch < 16; ++ch) {
        const unsigned short* p1 = y1 + (size_t)ch * YPLANE;
        ushort8 a8 = *(const ushort8*)p1;
        unsigned at = *(const unsigned*)(p1 + 8);
        float a[8];
#pragma unroll
        for (int j = 0; j < 7; ++j) a[j] = bf2f(a8[j + 1]);
        a[7] = bf2f((unsigned short)(at & 0xffffu));

        const unsigned short* p2 = y2 + (size_t)ch * YPLANE;
#pragma unroll
        for (int dy = 0; dy < 3; ++dy) {
            const unsigned short* pr = p2 + dy * PW;
            ushort8 b8 = *(const ushort8*)pr;
            unsigned bt = *(const unsigned*)(pr + 8);
            float w[10];
#pragma unroll
            for (int j = 0; j < 8; ++j) w[j] = bf2f(b8[j]);
            w[8] = bf2f((unsigned short)(bt & 0xffffu));
            w[9] = bf2f((unsigned short)(bt >> 16));
#pragma unroll
            for (int dx = 0; dx < 3; ++dx) {
                int k = dy * 3 + dx;
#pragma unroll
                for (int px = 0; px < 8; ++px)
                    acc[k][px] = fmaf(a[px], w[px + dx], acc[k][px]);
            }
        }
    }

    // reduce across the 4 ch-quarter lanes (xor 1, xor 2)
#pragma unroll
    for (int k = 0; k < 9; ++k)
#pragma unroll
        for (int px = 0; px < 8; ++px) {
            float v = acc[k][px];
            v += __shfl_xor(v, 1);
            v += __shfl_xor(v, 2);
            acc[k][px] = v;
        }

    if (h == 0) {
        float* cp = cv + (size_t)nt * 9 * HW + r * WIDTH + c0;
        const float rcr = 1.0f / CR;
#pragma unroll
        for (int k = 0; k < 9; ++k) {
            float sc = g[k] * BN_INV, bv = bb[k];
            f32x4 lo, hi;
            lo.x = relu(fmaf(acc[k][0] * rcr, sc, bv));
            lo.y = relu(fmaf(acc[k][1] * rcr, sc, bv));
            lo.z = relu(fmaf(acc[k][2] * rcr, sc, bv));
            lo.w = relu(fmaf(acc[k][3] * rcr, sc, bv));
            hi.x = relu(fmaf(acc[k][4] * rcr, sc, bv));
            hi.y = relu(fmaf(acc[k][5] * rcr, sc, bv));
            hi.z = relu(fmaf(acc[k][6] * rcr, sc, bv));
            hi.w = relu(fmaf(acc[k][7] * rcr, sc, bv));
            *(f32x4*)(cp + (size_t)k * HW)     = lo;
            *(f32x4*)(cp + (size_t)k * HW + 4) = hi;
        }
    }
}

// k3: out = relu(bn23(conv22(cv)) + x).  (round-5 proven)
// 2 pixels/thread (float2), 392 blocks x 256 thr; uniform o-loop -> s_loads.
__global__ __launch_bounds__(256) void k3_conv22(const float* __restrict__ cv,
                                                 const float* __restrict__ w2,
                                                 const float* __restrict__ g,
                                                 const float* __restrict__ bb,
                                                 const float* __restrict__ x,
                                                 float* __restrict__ out) {
    int gt = blockIdx.x * 256 + threadIdx.x;   // 0..100351
    int nt = gt / 1568;                        // 1568 = 3136/2
    int p2 = (gt - nt * 1568) * 2;

    const float* cp = cv + (size_t)nt * 9 * HW + p2;
    float cvx[9], cvy[9];
#pragma unroll
    for (int k = 0; k < 9; ++k) {
        f32x2 v = *(const f32x2*)(cp + (size_t)k * HW);
        cvx[k] = v.x; cvy[k] = v.y;
    }

    const float* xp = x   + (size_t)nt * (C * HW) + p2;
    float*       op = out + (size_t)nt * (C * HW) + p2;

#pragma unroll 8
    for (int o = 0; o < C; ++o) {
        const float* wr = w2 + o * 9;
        f32x2 xr = *(const f32x2*)(xp + (size_t)o * HW);
        float sx = 0.0f, sy = 0.0f;
#pragma unroll
        for (int k = 0; k < 9; ++k) {
            float wv = wr[k];
            sx = fmaf(wv, cvx[k], sx);
            sy = fmaf(wv, cvy[k], sy);
        }
        float sc = g[o] * BN_INV, bv = bb[o];
        f32x2 rv;
        rv.x = relu(fmaf(sx, sc, bv) + xr.x);
        rv.y = relu(fmaf(sy, sc, bv) + xr.y);
        *(f32x2*)(op + (size_t)o * HW) = rv;
    }
}

extern "C" void kernel_launch(void* const* d_in, const int* in_sizes, int n_in,
                              void* d_out, int out_size, void* d_ws, size_t ws_size,
                              hipStream_t stream) {
    const float* x   = (const float*)d_in[0];
    const float* w21 = (const float*)d_in[1];
    const float* g21 = (const float*)d_in[2];
    const float* b21 = (const float*)d_in[3];
    const float* g22 = (const float*)d_in[4];
    const float* b22 = (const float*)d_in[5];
    const float* w22 = (const float*)d_in[6];
    const float* g23 = (const float*)d_in[7];
    const float* b23 = (const float*)d_in[8];
    float* out = (float*)d_out;

    // ws: y bf16 padded (30.4MB) | cv fp32 (7.2MB) | wbf (32KB)
    unsigned short* yb  = (unsigned short*)d_ws;
    float*          cvb = (float*)((char*)d_ws + YBYTES);
    unsigned short* wbf = (unsigned short*)((char*)d_ws + YBYTES + CVBYTES);

    k0_cvt_w <<<64,   256, 0, stream>>>(w21, wbf);
    k1_mfma  <<<3200, 256, 0, stream>>>(x, wbf, g21, b21, yb);   // 3136 tiles + 64 halo
    k2_corr  <<<392,  256, 0, stream>>>(yb, g22, b22, cvb);
    k3_conv22<<<392,  256, 0, stream>>>(cvb, w22, g23, b23, x, out);
}

// Round 13
// 191.771 us; speedup vs baseline: 1.0548x; 1.0502x over previous
//
#include <hip/hip_runtime.h>

#define HW     3136      // 56*56
#define WIDTH  56
#define C      256
#define CR     64
#define NT     64
#define TT     8
#define PW     64        // padded row width (bf16 y)
#define PH     58        // padded rows
#define YPLANE (PH*PW)   // 3712 shorts per (nt,ch) plane
#define YBYTES ((size_t)NT * CR * YPLANE * 2)        // 30,408,704
#define CVBYTES ((size_t)NT * 9 * HW * 4)            // 7,225,344

#define BN_INV 0.9999950000374997f   // 1/sqrt(1+1e-5)

typedef __attribute__((ext_vector_type(8))) short short8;
typedef __attribute__((ext_vector_type(4))) short s16x4;
typedef __attribute__((ext_vector_type(8))) unsigned short ushort8;
typedef __attribute__((ext_vector_type(4))) float f32x4;
typedef __attribute__((ext_vector_type(2))) float f32x2;

static __device__ __forceinline__ float relu(float v) { return fmaxf(v, 0.0f); }
static __device__ __forceinline__ float bf2f(unsigned short u) {
    return __builtin_bit_cast(float, (unsigned)u << 16);
}
static __device__ __forceinline__ unsigned short f2bf(float f) {
    unsigned u = __builtin_bit_cast(unsigned, f);
    unsigned r = (u + 0x7FFFu + ((u >> 16) & 1u)) >> 16;   // RNE
    return (unsigned short)r;
}
static __device__ __forceinline__ unsigned pack2(float a, float b) {
    return (unsigned)f2bf(a) | ((unsigned)f2bf(b) << 16);
}

// k0: conv21_w fp32 [64][256] -> bf16
__global__ __launch_bounds__(256) void k0_cvt_w(const float* __restrict__ w,
                                                unsigned short* __restrict__ wbf) {
    int i = blockIdx.x * 256 + threadIdx.x;
    wbf[i] = f2bf(w[i]);
}

// zero the halo cells of all 64 planes of frame nt
static __device__ __forceinline__ void halo_zero(int nt, int tid,
                                                 unsigned short* __restrict__ y) {
    const int ch = tid >> 2, part = tid & 3;
    unsigned short* pl = y + ((size_t)nt * CR + ch) * YPLANE;
    if (part == 0) {
        ushort8 z = (ushort8)0;
#pragma unroll
        for (int j = 0; j < 8; ++j) *(ushort8*)(pl + j * 8) = z;          // row 0
    } else if (part == 1) {
        ushort8 z = (ushort8)0;
        unsigned short* q = pl + 57 * PW;                                  // row 57
#pragma unroll
        for (int j = 0; j < 8; ++j) *(ushort8*)(q + j * 8) = z;
    } else if (part == 2) {
        for (int r = 1; r <= 28; ++r) {
            unsigned short* q = pl + r * PW + 57;
#pragma unroll
            for (int j = 0; j < 8; ++j) q[j] = 0;
        }
    } else {
        for (int r = 29; r <= 56; ++r) {
            unsigned short* q = pl + r * PW + 57;
#pragma unroll
            for (int j = 0; j < 8; ++j) q[j] = 0;
        }
        pl[PW] = 0;                                                        // row 1 col 0
    }
}

// k1: y = relu(bn21(conv21(x))) via MFMA, bf16 padded output.
// Block = NPX-px span of one frame. Staging: thread loads NPX/32 float4 at
// flat idx j*256+tid -> 4KB contiguous per block-instr (sequential walk of x),
// packs bf16, 8B ds_write into Bl[c][px] (transpose in LDS). B-frags = 8 u16
// LDS reads; A-frags from L2-hot wbf. 2 barriers/K-step (R2-proven), next-ks
// loads issued between them; 2 blocks/CU overlap.
template<int NPX>
__global__ __launch_bounds__(256) void k1_mfma(const float* __restrict__ x,
                                               const unsigned short* __restrict__ wbf,
                                               const float* __restrict__ g,
                                               const float* __restrict__ bb,
                                               unsigned short* __restrict__ y) {
    constexpr int NFR = NPX / 64;        // n-frags per wave (6 | 1)
    constexpr int NF4 = NPX / 32;        // float4 loads per thread per ks (12 | 2)
    constexpr int NPW = NPX / 4;         // px per wave (96 | 16)
    constexpr int RS  = (NPX == 384) ? 394 : 66;   // row stride (u16); 8*RS/2 % 32 == 8
    __shared__ unsigned short Bl[32][RS];

    const int tid  = threadIdx.x;
    const int lane = tid & 63;
    const int wv   = tid >> 6;
    const int frow = lane & 15;
    const int hi   = lane >> 4;

    int nt, px0;
    if (NPX == 384) {
        if (blockIdx.x >= 512) { halo_zero(blockIdx.x - 512, tid, y); return; }
        nt = blockIdx.x >> 3; px0 = (blockIdx.x & 7) * 384;
    } else {
        nt = blockIdx.x; px0 = 3072;
    }

    const float* xbase = x + (size_t)nt * (C * HW) + px0;
    const unsigned short* ab = wbf + frow * C + hi * 8;

    // per-thread staging coordinates (constant across ks)
    int goff[NF4];   // dword offset into xbase for ks=0
    int doff[NF4];   // byte offset into Bl
#pragma unroll
    for (int j = 0; j < NF4; ++j) {
        int f  = j * 256 + tid;          // flat float4 index
        int c  = f / (NPX / 4);
        int p4 = f - c * (NPX / 4);
        goff[j] = c * HW + p4 * 4;
        doff[j] = (c * RS + p4 * 4) * 2;
    }

    f32x4 acc[NFR][4];
#pragma unroll
    for (int nb = 0; nb < NFR; ++nb)
#pragma unroll
        for (int mb = 0; mb < 4; ++mb) acc[nb][mb] = (f32x4)0.0f;

    f32x4 xq[NF4];

#define ISSUE(KS)                                                           \
    _Pragma("unroll")                                                       \
    for (int j = 0; j < NF4; ++j)                                           \
        xq[j] = *(const f32x4*)(xbase + (size_t)(KS) * (32 * HW) + goff[j]);

#define PACKW                                                               \
    _Pragma("unroll")                                                       \
    for (int j = 0; j < NF4; ++j) {                                         \
        union { unsigned d[2]; s16x4 v; } pk;                               \
        pk.d[0] = pack2(xq[j].x, xq[j].y);                                  \
        pk.d[1] = pack2(xq[j].z, xq[j].w);                                  \
        *(s16x4*)((char*)&Bl[0][0] + doff[j]) = pk.v;                       \
    }

    ISSUE(0)

#pragma unroll
    for (int ks = 0; ks < 8; ++ks) {
        __syncthreads();                 // consumers of previous tile done
        PACKW                            // xq(ks) -> LDS
        if (ks < 7) { ISSUE(ks + 1) }    // refill xq; in flight across compute
        __syncthreads();                 // tile ready

        short8 afr[4];
#pragma unroll
        for (int mb = 0; mb < 4; ++mb)
            afr[mb] = *(const short8*)(ab + mb * 16 * C + ks * 32);

#pragma unroll
        for (int nb = 0; nb < NFR; ++nb) {
            const int px = wv * NPW + nb * 16 + frow;
            short8 bf;
#pragma unroll
            for (int j = 0; j < 8; ++j)
                bf[j] = (short)Bl[hi * 8 + j][px];
#pragma unroll
            for (int mb = 0; mb < 4; ++mb)
                acc[nb][mb] = __builtin_amdgcn_mfma_f32_16x16x32_bf16(
                    afr[mb], bf, acc[nb][mb], 0, 0, 0);
        }
    }
#undef ISSUE
#undef PACKW

    // epilogue: D col = lane&15 (pixel), row = hi*4 + rr (output o); bf16 store
    unsigned short* ybase = y + (size_t)nt * CR * YPLANE;
#pragma unroll
    for (int nb = 0; nb < NFR; ++nb) {
        const int p = px0 + wv * NPW + nb * 16 + frow;
        const int r = p / WIDTH;
        const int c = p - r * WIDTH;
        const int pidx = (r + 1) * PW + (c + 1);
#pragma unroll
        for (int mb = 0; mb < 4; ++mb)
#pragma unroll
            for (int rr = 0; rr < 4; ++rr) {
                int o = mb * 16 + hi * 4 + rr;
                float v = relu(fmaf(acc[nb][mb][rr], g[o] * BN_INV, bb[o]));
                ybase[(size_t)o * YPLANE + pidx] = f2bf(v);
            }
    }
}

// k2: cv[nt,k,p] = relu(bn22( (1/CR) * sum_ch y1*y2(shifted) )).  (round-5 proven)
__global__ __launch_bounds__(256) void k2_corr(const unsigned short* __restrict__ y,
                                               const float* __restrict__ g,
                                               const float* __restrict__ bb,
                                               float* __restrict__ cv) {
    int gt   = blockIdx.x * 256 + threadIdx.x;   // 0..100351
    int h    = gt & 3;                           // ch quarter
    int task = gt >> 2;                          // 0..25087
    int nt   = task / 392;                       // 392 = 56 rows * 7 cgroups
    int rm   = task - nt * 392;
    int r    = rm / 7;
    int cg   = rm - r * 7;
    int c0   = cg * 8;
    int nt2  = ((nt & (TT - 1)) < TT - 1) ? nt + 1 : nt;

    const unsigned short* y1 = y + ((size_t)nt * CR + h * 16) * YPLANE
                                 + (size_t)(r + 1) * PW + c0;
    const unsigned short* y2 = y + ((size_t)nt2 * CR + h * 16) * YPLANE
                                 + (size_t)r * PW + c0;

    float acc[9][8];
#pragma unroll
    for (int k = 0; k < 9; ++k)
#pragma unroll
        for (int px = 0; px < 8; ++px) acc[k][px] = 0.0f;

#pragma unroll 2
    for (int ch = 0; ch < 16; ++ch) {
        const unsigned short* p1 = y1 + (size_t)ch * YPLANE;
        ushort8 a8 = *(const ushort8*)p1;
        unsigned at = *(const unsigned*)(p1 + 8);
        float a[8];
#pragma unroll
        for (int j = 0; j < 7; ++j) a[j] = bf2f(a8[j + 1]);
        a[7] = bf2f((unsigned short)(at & 0xffffu));

        const unsigned short* p2 = y2 + (size_t)ch * YPLANE;
#pragma unroll
        for (int dy = 0; dy < 3; ++dy) {
            const unsigned short* pr = p2 + dy * PW;
            ushort8 b8 = *(const ushort8*)pr;
            unsigned bt = *(const unsigned*)(pr + 8);
            float w[10];
#pragma unroll
            for (int j = 0; j < 8; ++j) w[j] = bf2f(b8[j]);
            w[8] = bf2f((unsigned short)(bt & 0xffffu));
            w[9] = bf2f((unsigned short)(bt >> 16));
#pragma unroll
            for (int dx = 0; dx < 3; ++dx) {
                int k = dy * 3 + dx;
#pragma unroll
                for (int px = 0; px < 8; ++px)
                    acc[k][px] = fmaf(a[px], w[px + dx], acc[k][px]);
            }
        }
    }

    // reduce across the 4 ch-quarter lanes (xor 1, xor 2)
#pragma unroll
    for (int k = 0; k < 9; ++k)
#pragma unroll
        for (int px = 0; px < 8; ++px) {
            float v = acc[k][px];
            v += __shfl_xor(v, 1);
            v += __shfl_xor(v, 2);
            acc[k][px] = v;
        }

    if (h == 0) {
        float* cp = cv + (size_t)nt * 9 * HW + r * WIDTH + c0;
        const float rcr = 1.0f / CR;
#pragma unroll
        for (int k = 0; k < 9; ++k) {
            float sc = g[k] * BN_INV, bv = bb[k];
            f32x4 lo, hi;
            lo.x = relu(fmaf(acc[k][0] * rcr, sc, bv));
            lo.y = relu(fmaf(acc[k][1] * rcr, sc, bv));
            lo.z = relu(fmaf(acc[k][2] * rcr, sc, bv));
            lo.w = relu(fmaf(acc[k][3] * rcr, sc, bv));
            hi.x = relu(fmaf(acc[k][4] * rcr, sc, bv));
            hi.y = relu(fmaf(acc[k][5] * rcr, sc, bv));
            hi.z = relu(fmaf(acc[k][6] * rcr, sc, bv));
            hi.w = relu(fmaf(acc[k][7] * rcr, sc, bv));
            *(f32x4*)(cp + (size_t)k * HW)     = lo;
            *(f32x4*)(cp + (size_t)k * HW + 4) = hi;
        }
    }
}

// k3: out = relu(bn23(conv22(cv)) + x).  (round-5 proven)
__global__ __launch_bounds__(256) void k3_conv22(const float* __restrict__ cv,
                                                 const float* __restrict__ w2,
                                                 const float* __restrict__ g,
                                                 const float* __restrict__ bb,
                                                 const float* __restrict__ x,
                                                 float* __restrict__ out) {
    int gt = blockIdx.x * 256 + threadIdx.x;   // 0..100351
    int nt = gt / 1568;                        // 1568 = 3136/2
    int p2 = (gt - nt * 1568) * 2;

    const float* cp = cv + (size_t)nt * 9 * HW + p2;
    float cvx[9], cvy[9];
#pragma unroll
    for (int k = 0; k < 9; ++k) {
        f32x2 v = *(const f32x2*)(cp + (size_t)k * HW);
        cvx[k] = v.x; cvy[k] = v.y;
    }

    const float* xp = x   + (size_t)nt * (C * HW) + p2;
    float*       op = out + (size_t)nt * (C * HW) + p2;

#pragma unroll 8
    for (int o = 0; o < C; ++o) {
        const float* wr = w2 + o * 9;
        f32x2 xr = *(const f32x2*)(xp + (size_t)o * HW);
        float sx = 0.0f, sy = 0.0f;
#pragma unroll
        for (int k = 0; k < 9; ++k) {
            float wv = wr[k];
            sx = fmaf(wv, cvx[k], sx);
            sy = fmaf(wv, cvy[k], sy);
        }
        float sc = g[o] * BN_INV, bv = bb[o];
        f32x2 rv;
        rv.x = relu(fmaf(sx, sc, bv) + xr.x);
        rv.y = relu(fmaf(sy, sc, bv) + xr.y);
        *(f32x2*)(op + (size_t)o * HW) = rv;
    }
}

extern "C" void kernel_launch(void* const* d_in, const int* in_sizes, int n_in,
                              void* d_out, int out_size, void* d_ws, size_t ws_size,
                              hipStream_t stream) {
    const float* x   = (const float*)d_in[0];
    const float* w21 = (const float*)d_in[1];
    const float* g21 = (const float*)d_in[2];
    const float* b21 = (const float*)d_in[3];
    const float* g22 = (const float*)d_in[4];
    const float* b22 = (const float*)d_in[5];
    const float* w22 = (const float*)d_in[6];
    const float* g23 = (const float*)d_in[7];
    const float* b23 = (const float*)d_in[8];
    float* out = (float*)d_out;

    // ws: y bf16 padded (30.4MB) | cv fp32 (7.2MB) | wbf (32KB)
    unsigned short* yb  = (unsigned short*)d_ws;
    float*          cvb = (float*)((char*)d_ws + YBYTES);
    unsigned short* wbf = (unsigned short*)((char*)d_ws + YBYTES + CVBYTES);

    k0_cvt_w    <<<64,  256, 0, stream>>>(w21, wbf);
    k1_mfma<384><<<576, 256, 0, stream>>>(x, wbf, g21, b21, yb);  // 512 tiles + 64 halo
    k1_mfma<64> <<<64,  256, 0, stream>>>(x, wbf, g21, b21, yb);  // px 3072..3135
    k2_corr     <<<392, 256, 0, stream>>>(yb, g22, b22, cvb);
    k3_conv22   <<<392, 256, 0, stream>>>(cvb, w22, g23, b23, x, out);
}